// Round 4
// baseline (9322.122 us; speedup 1.0000x reference)
//
#include <hip/hip_runtime.h>

typedef __attribute__((ext_vector_type(8))) short short8;
typedef __attribute__((ext_vector_type(4))) float f32x4;
typedef __attribute__((ext_vector_type(4))) unsigned u32x4;

__device__ __forceinline__ unsigned short f2bf(float f) {
  unsigned int u = __float_as_uint(f);
  u = (u + 0x7fffu + ((u >> 16) & 1u)) >> 16;
  return (unsigned short)u;
}

__device__ __forceinline__ void xp_store(float* p, float v) { *p = v; }
__device__ __forceinline__ void xp_store(unsigned short* p, float v) { *p = f2bf(v); }
__device__ __forceinline__ float xp_load(const float* p) { return *p; }
__device__ __forceinline__ float xp_load(const unsigned short* p) {
  return __uint_as_float(((unsigned int)*p) << 16);
}

// ---------------- prep: pack W_x (f32 -> bf16 pairs) ----------------
__global__ void prep_wx(const float* __restrict__ W, unsigned int* __restrict__ Wx2) {
  int i = blockIdx.x * 256 + threadIdx.x;  // 1024*128 dwords
  int g = i >> 7, kk = i & 127;
  float lo = W[(size_t)g * 512 + 256 + 2 * kk];
  float hi = W[(size_t)g * 512 + 256 + 2 * kk + 1];
  Wx2[i] = (unsigned int)f2bf(lo) | ((unsigned int)f2bf(hi) << 16);
}

// ---------------- GEMM: xp[m][g] = sum_k x[m][k] * Wx[g][k] + b[g] ----------------
template <typename XPT>
__global__ __launch_bounds__(256, 4) void gemm_xp(const float* __restrict__ x,
                                                  const unsigned int* __restrict__ Wx2,
                                                  const float* __restrict__ bias,
                                                  XPT* __restrict__ xp) {
  __shared__ unsigned short As[128][40];
  __shared__ unsigned short Bs[128][40];
  const int m0 = blockIdx.y * 128, n0 = blockIdx.x * 128;
  const int tid = threadIdx.x, lane = tid & 63, w = tid >> 6;
  const int wr = w >> 1, wc = w & 1;
  const int r16 = lane & 15, kq = lane >> 4;
  f32x4 acc[4][4];
#pragma unroll
  for (int m = 0; m < 4; m++)
#pragma unroll
    for (int n = 0; n < 4; n++)
#pragma unroll
      for (int j = 0; j < 4; j++) acc[m][n][j] = 0.f;

  for (int kb = 0; kb < 256; kb += 32) {
    __syncthreads();
#pragma unroll
    for (int i = 0; i < 4; i++) {
      int idx = tid + i * 256;
      int row = idx >> 3, c4 = idx & 7;
      float4 v = *(const float4*)(x + (size_t)(m0 + row) * 256 + kb + c4 * 4);
      ushort4 s;
      s.x = f2bf(v.x); s.y = f2bf(v.y); s.z = f2bf(v.z); s.w = f2bf(v.w);
      *(ushort4*)&As[row][c4 * 4] = s;
    }
#pragma unroll
    for (int i = 0; i < 2; i++) {
      int idx = tid + i * 256;
      int row = idx >> 2, c = idx & 3;
      uint4 v = *(const uint4*)(Wx2 + (size_t)(n0 + row) * 128 + (kb >> 1) + c * 4);
      *(uint4*)&Bs[row][c * 8] = v;
    }
    __syncthreads();
    short8 a[4], bb[4];
#pragma unroll
    for (int m = 0; m < 4; m++)
      a[m] = *(const short8*)&As[wr * 64 + m * 16 + r16][kq * 8];
#pragma unroll
    for (int n = 0; n < 4; n++)
      bb[n] = *(const short8*)&Bs[wc * 64 + n * 16 + r16][kq * 8];
#pragma unroll
    for (int m = 0; m < 4; m++)
#pragma unroll
      for (int n = 0; n < 4; n++)
        acc[m][n] = __builtin_amdgcn_mfma_f32_16x16x32_bf16(a[m], bb[n], acc[m][n], 0, 0, 0);
  }
#pragma unroll
  for (int n = 0; n < 4; n++) {
    int gn = n0 + wc * 64 + n * 16 + r16;
    float bi = bias[gn];
#pragma unroll
    for (int m = 0; m < 4; m++) {
      int gm = m0 + wr * 64 + m * 16 + kq * 4;
#pragma unroll
      for (int j = 0; j < 4; j++) {
        xp_store(&xp[(size_t)(gm + j) * 1024 + gn], acc[m][n][j] + bi);
      }
    }
  }
}

// ---------------- recurrence: self-stamped device-scope h exchange -----------------
// 4 WGs per batch; WG q owns units [q*64, q*64+64). Thread (u=tid>>3, ks=tid&7) holds
// all four gate rows of unit u over K-slice [ks*32, ks*32+32); a 3-round intra-8-lane
// butterfly leaves the complete f,i,g,o in every lane -> in-register c/h update
// (redundant x8, deterministic). Exchange: each published dword = (bf16(h)<<16)|(t+1).
// Data and flag are one word, so freshness is per-dword self-validating: readers
// re-issue 8x global_load_dwordx4 (sc0 sc1 = device-scope/MALL, placement-oblivious)
// until all 32 stamps == t. Stamp induction: a wave writes stamp t+2 into a slot only
// after observing all stamps == t+1, i.e. after every wave finished reading stamp-t
// data -> 2 slots suffice, and while polling for t only {t-2, t} can appear.
// hbuf is zeroed each launch so stale stamps from a prior replay never validate.
template <typename XPT>
__global__ __launch_bounds__(512, 2) void lstm_rec(const float* __restrict__ W,
                                                   const XPT* __restrict__ xp,
                                                   float* __restrict__ out,
                                                   unsigned* __restrict__ hbuf) {
  const int tid = threadIdx.x;
  const int b = blockIdx.x & 63, q = blockIdx.x >> 6;
  const int ks = tid & 7, u = tid >> 3;
  const int gu = (q << 6) + u;

  // weights: 4 gate rows x 32-K-slice, register-resident f32
  float w[4][32];
#pragma unroll
  for (int g = 0; g < 4; g++) {
    const float* rp = W + (size_t)(g * 256 + gu) * 512 + (ks << 5);
#pragma unroll
    for (int i = 0; i < 8; i++) {
      f32x4 v = *(const f32x4*)(rp + (i << 2));
      w[g][i * 4 + 0] = v[0];
      w[g][i * 4 + 1] = v[1];
      w[g][i * 4 + 2] = v[2];
      w[g][i * 4 + 3] = v[3];
    }
  }

  unsigned* hb = hbuf + ((size_t)b << 9);  // 2 slots x 256 stamped dwords
  const size_t xpb = (size_t)b << 10;

  float xv0, xv1, xv2, xv3;
  {
    const XPT* xr = &xp[xpb * 1024 + gu];
    xv0 = xp_load(xr); xv1 = xp_load(xr + 256);
    xv2 = xp_load(xr + 512); xv3 = xp_load(xr + 768);
  }
  float c = 0.f;
  float hv[32];

  for (int t = 0; t < 1024; t++) {
    if (t > 0) {
      const unsigned* hs = hb + (((t - 1) & 1) << 8) + (ks << 5);
      const unsigned tpat = (unsigned)t;
      u32x4 r0, r1, r2, r3, r4, r5, r6, r7;
      for (;;) {
        asm volatile(
            "global_load_dwordx4 %0, %8, off sc0 sc1\n\t"
            "global_load_dwordx4 %1, %8, off offset:16 sc0 sc1\n\t"
            "global_load_dwordx4 %2, %8, off offset:32 sc0 sc1\n\t"
            "global_load_dwordx4 %3, %8, off offset:48 sc0 sc1\n\t"
            "global_load_dwordx4 %4, %8, off offset:64 sc0 sc1\n\t"
            "global_load_dwordx4 %5, %8, off offset:80 sc0 sc1\n\t"
            "global_load_dwordx4 %6, %8, off offset:96 sc0 sc1\n\t"
            "global_load_dwordx4 %7, %8, off offset:112 sc0 sc1\n\t"
            "s_waitcnt vmcnt(0)"
            : "=&v"(r0), "=&v"(r1), "=&v"(r2), "=&v"(r3),
              "=&v"(r4), "=&v"(r5), "=&v"(r6), "=&v"(r7)
            : "v"(hs)
            : "memory");
        unsigned acc;
        acc  = (r0[0] ^ tpat) | (r0[1] ^ tpat) | (r0[2] ^ tpat) | (r0[3] ^ tpat);
        acc |= (r1[0] ^ tpat) | (r1[1] ^ tpat) | (r1[2] ^ tpat) | (r1[3] ^ tpat);
        acc |= (r2[0] ^ tpat) | (r2[1] ^ tpat) | (r2[2] ^ tpat) | (r2[3] ^ tpat);
        acc |= (r3[0] ^ tpat) | (r3[1] ^ tpat) | (r3[2] ^ tpat) | (r3[3] ^ tpat);
        acc |= (r4[0] ^ tpat) | (r4[1] ^ tpat) | (r4[2] ^ tpat) | (r4[3] ^ tpat);
        acc |= (r5[0] ^ tpat) | (r5[1] ^ tpat) | (r5[2] ^ tpat) | (r5[3] ^ tpat);
        acc |= (r6[0] ^ tpat) | (r6[1] ^ tpat) | (r6[2] ^ tpat) | (r6[3] ^ tpat);
        acc |= (r7[0] ^ tpat) | (r7[1] ^ tpat) | (r7[2] ^ tpat) | (r7[3] ^ tpat);
        if (__all((int)((acc & 0xFFFFu) == 0u))) break;
      }
#pragma unroll
      for (int j = 0; j < 4; j++) {
        hv[0 + j]  = __uint_as_float(r0[j] & 0xFFFF0000u);
        hv[4 + j]  = __uint_as_float(r1[j] & 0xFFFF0000u);
        hv[8 + j]  = __uint_as_float(r2[j] & 0xFFFF0000u);
        hv[12 + j] = __uint_as_float(r3[j] & 0xFFFF0000u);
        hv[16 + j] = __uint_as_float(r4[j] & 0xFFFF0000u);
        hv[20 + j] = __uint_as_float(r5[j] & 0xFFFF0000u);
        hv[24 + j] = __uint_as_float(r6[j] & 0xFFFF0000u);
        hv[28 + j] = __uint_as_float(r7[j] & 0xFFFF0000u);
      }
    } else {
#pragma unroll
      for (int i = 0; i < 32; i++) hv[i] = 0.f;
    }

    float a0 = 0.f, a1 = 0.f, a2 = 0.f, a3 = 0.f;
#pragma unroll
    for (int i = 0; i < 32; i++) {
      a0 = fmaf(w[0][i], hv[i], a0);
      a1 = fmaf(w[1][i], hv[i], a1);
      a2 = fmaf(w[2][i], hv[i], a2);
      a3 = fmaf(w[3][i], hv[i], a3);
    }
#pragma unroll
    for (int d = 1; d < 8; d <<= 1) {
      a0 += __shfl_xor(a0, d, 64);
      a1 += __shfl_xor(a1, d, 64);
      a2 += __shfl_xor(a2, d, 64);
      a3 += __shfl_xor(a3, d, 64);
    }

    float gf = a0 + xv0, gi = a1 + xv1, gg = a2 + xv2, go = a3 + xv3;
    float f = 1.f / (1.f + __expf(-gf));
    float ii = 1.f / (1.f + __expf(-gi));
    float eg = __expf(2.f * gg);
    float gt = (eg - 1.f) / (eg + 1.f);
    float o = 1.f / (1.f + __expf(-go));
    c = f * c + ii * gt;
    float ec = __expf(2.f * c);
    float tc = (ec - 1.f) / (ec + 1.f);
    float h = o * tc;

    // publish: one self-stamped dword per unit (earliest possible, device scope)
    if (ks == 0) {
      unsigned dw = ((unsigned)f2bf(h) << 16) | (unsigned)(t + 1);
      unsigned* hp = hb + ((t & 1) << 8) + gu;
      asm volatile("global_store_dword %0, %1, off sc0 sc1" ::"v"(hp), "v"(dw) : "memory");
      __builtin_nontemporal_store(h, &out[(xpb + t) * 256 + gu]);
    }

    if (t < 1023) {
      const XPT* xr = &xp[(xpb + t + 1) * 1024 + gu];
      xv0 = xp_load(xr); xv1 = xp_load(xr + 256);
      xv2 = xp_load(xr + 512); xv3 = xp_load(xr + 768);
    } else if (ks == 0) {
      out[16777216 + b * 256 + gu] = h;           // h_fin
      out[16777216 + 16384 + b * 256 + gu] = c;   // c_fin
    }
  }
}

extern "C" void kernel_launch(void* const* d_in, const int* in_sizes, int n_in,
                              void* d_out, int out_size, void* d_ws, size_t ws_size,
                              hipStream_t stream) {
  (void)in_sizes; (void)n_in; (void)out_size;
  const float* x = (const float*)d_in[0];
  const float* W = (const float*)d_in[1];
  const float* bias = (const float*)d_in[2];
  float* out = (float*)d_out;
  char* ws = (char*)d_ws;

  unsigned int* Wx2 = (unsigned int*)ws;       // 524288 B
  unsigned int* hbuf = (unsigned int*)(ws + 524288);  // 131072 B (64 b x 2 x 256 dwords)
  char* xpmem = ws + 1048576;

  const size_t need32 = 1048576 + (size_t)65536 * 1024 * 4;

  hipMemsetAsync(hbuf, 0, 131072, stream);  // stale stamps must never validate
  prep_wx<<<512, 256, 0, stream>>>(W, Wx2);

  if (ws_size >= need32) {
    gemm_xp<float><<<dim3(8, 512), 256, 0, stream>>>(x, Wx2, bias, (float*)xpmem);
    lstm_rec<float><<<256, 512, 0, stream>>>(W, (const float*)xpmem, out, hbuf);
  } else {
    gemm_xp<unsigned short><<<dim3(8, 512), 256, 0, stream>>>(x, Wx2, bias,
                                                              (unsigned short*)xpmem);
    lstm_rec<unsigned short><<<256, 512, 0, stream>>>(W, (const unsigned short*)xpmem, out,
                                                      hbuf);
  }
}

// Round 5
// 4914.073 us; speedup vs baseline: 1.8970x; 1.8970x over previous
//
#include <hip/hip_runtime.h>

typedef __attribute__((ext_vector_type(8))) short short8;
typedef __attribute__((ext_vector_type(4))) float f32x4;
typedef __attribute__((ext_vector_type(4))) unsigned u32x4;

__device__ __forceinline__ unsigned short f2bf(float f) {
  unsigned int u = __float_as_uint(f);
  u = (u + 0x7fffu + ((u >> 16) & 1u)) >> 16;
  return (unsigned short)u;
}

__device__ __forceinline__ void xp_store(float* p, float v) { *p = v; }
__device__ __forceinline__ void xp_store(unsigned short* p, float v) { *p = f2bf(v); }
__device__ __forceinline__ float xp_load(const float* p) { return *p; }
__device__ __forceinline__ float xp_load(const unsigned short* p) {
  return __uint_as_float(((unsigned int)*p) << 16);
}

// ---------------- prep: pack W_x (f32 -> bf16 pairs) ----------------
__global__ void prep_wx(const float* __restrict__ W, unsigned int* __restrict__ Wx2) {
  int i = blockIdx.x * 256 + threadIdx.x;  // 1024*128 dwords
  int g = i >> 7, kk = i & 127;
  float lo = W[(size_t)g * 512 + 256 + 2 * kk];
  float hi = W[(size_t)g * 512 + 256 + 2 * kk + 1];
  Wx2[i] = (unsigned int)f2bf(lo) | ((unsigned int)f2bf(hi) << 16);
}

// ---------------- GEMM: xp[m][g] = sum_k x[m][k] * Wx[g][k] + b[g] ----------------
template <typename XPT>
__global__ __launch_bounds__(256, 4) void gemm_xp(const float* __restrict__ x,
                                                  const unsigned int* __restrict__ Wx2,
                                                  const float* __restrict__ bias,
                                                  XPT* __restrict__ xp) {
  __shared__ unsigned short As[128][40];
  __shared__ unsigned short Bs[128][40];
  const int m0 = blockIdx.y * 128, n0 = blockIdx.x * 128;
  const int tid = threadIdx.x, lane = tid & 63, w = tid >> 6;
  const int wr = w >> 1, wc = w & 1;
  const int r16 = lane & 15, kq = lane >> 4;
  f32x4 acc[4][4];
#pragma unroll
  for (int m = 0; m < 4; m++)
#pragma unroll
    for (int n = 0; n < 4; n++)
#pragma unroll
      for (int j = 0; j < 4; j++) acc[m][n][j] = 0.f;

  for (int kb = 0; kb < 256; kb += 32) {
    __syncthreads();
#pragma unroll
    for (int i = 0; i < 4; i++) {
      int idx = tid + i * 256;
      int row = idx >> 3, c4 = idx & 7;
      float4 v = *(const float4*)(x + (size_t)(m0 + row) * 256 + kb + c4 * 4);
      ushort4 s;
      s.x = f2bf(v.x); s.y = f2bf(v.y); s.z = f2bf(v.z); s.w = f2bf(v.w);
      *(ushort4*)&As[row][c4 * 4] = s;
    }
#pragma unroll
    for (int i = 0; i < 2; i++) {
      int idx = tid + i * 256;
      int row = idx >> 2, c = idx & 3;
      uint4 v = *(const uint4*)(Wx2 + (size_t)(n0 + row) * 128 + (kb >> 1) + c * 4);
      *(uint4*)&Bs[row][c * 8] = v;
    }
    __syncthreads();
    short8 a[4], bb[4];
#pragma unroll
    for (int m = 0; m < 4; m++)
      a[m] = *(const short8*)&As[wr * 64 + m * 16 + r16][kq * 8];
#pragma unroll
    for (int n = 0; n < 4; n++)
      bb[n] = *(const short8*)&Bs[wc * 64 + n * 16 + r16][kq * 8];
#pragma unroll
    for (int m = 0; m < 4; m++)
#pragma unroll
      for (int n = 0; n < 4; n++)
        acc[m][n] = __builtin_amdgcn_mfma_f32_16x16x32_bf16(a[m], bb[n], acc[m][n], 0, 0, 0);
  }
#pragma unroll
  for (int n = 0; n < 4; n++) {
    int gn = n0 + wc * 64 + n * 16 + r16;
    float bi = bias[gn];
#pragma unroll
    for (int m = 0; m < 4; m++) {
      int gm = m0 + wr * 64 + m * 16 + kq * 4;
#pragma unroll
      for (int j = 0; j < 4; j++) {
        xp_store(&xp[(size_t)(gm + j) * 1024 + gn], acc[m][n][j] + bi);
      }
    }
  }
}

// ---------------- recurrence: flag + bulk-load h exchange, device scope ------------
// 4 WGs per batch; WG q owns units [q*64, q*64+64). Thread (u=tid>>3, ks=tid&7) holds
// all four gate rows of unit u over K-slice [ks*32, ks*32+32) in 128 f32 VGPRs
// (launch_bounds(512,1) -> 256-VGPR budget; NO spill, verify VGPR_Count ~200).
// 3-round intra-8-lane butterfly -> every lane holds the unit's full f,i,g,o ->
// in-register c/h update (redundant x8, deterministic).
// Exchange per wave per step: 8 h dwords (bf16<<16, directly usable as f32) stored
// sc0 sc1 -> s_waitcnt vmcnt(0) -> per-wave flag := t+1 (sc0 sc1). Consumers poll the
// 32 flags of their batch with ONE coalesced 128B load until all >= t, then issue ONE
// 8x dwordx4 bulk load (1KB/wave, 8-way broadcast-coalesced). Skew <= 1: a wave's
// flag=t+1 implies its slot-(t-1) bulk reads retired (vmcnt(0) precedes the flag
// store), so 2 slots suffice. Flags are memset each launch (replay-safe).
template <typename XPT>
__global__ __launch_bounds__(512, 1) void lstm_rec(const float* __restrict__ W,
                                                   const XPT* __restrict__ xp,
                                                   float* __restrict__ out,
                                                   unsigned* __restrict__ hbuf,
                                                   unsigned* __restrict__ flags) {
  const int tid = threadIdx.x;
  const int b = blockIdx.x & 63, q = blockIdx.x >> 6;
  const int ks = tid & 7, u = tid >> 3;
  const int lane = tid & 63, wv = tid >> 6;
  const int gu = (q << 6) + u;

  // weights: 4 gate rows x 32-K-slice, register-resident f32 (128 VGPRs)
  float w[4][32];
#pragma unroll
  for (int g = 0; g < 4; g++) {
    const float* rp = W + (size_t)(g * 256 + gu) * 512 + (ks << 5);
#pragma unroll
    for (int i = 0; i < 8; i++) {
      f32x4 v = *(const f32x4*)(rp + (i << 2));
      w[g][i * 4 + 0] = v[0];
      w[g][i * 4 + 1] = v[1];
      w[g][i * 4 + 2] = v[2];
      w[g][i * 4 + 3] = v[3];
    }
  }

  unsigned* hb = hbuf + ((size_t)b << 9);          // 2 slots x 256 dwords
  const unsigned* fp = flags + b * 32 + (lane & 31);
  unsigned* fmine = flags + b * 32 + (q << 3) + wv;
  const size_t xpb = (size_t)b << 10;

  float xv0, xv1, xv2, xv3;
  {
    const XPT* xr = &xp[xpb * 1024 + gu];
    xv0 = xp_load(xr); xv1 = xp_load(xr + 256);
    xv2 = xp_load(xr + 512); xv3 = xp_load(xr + 768);
  }
  float c = 0.f;
  f32x4 hr[8];

  for (int t = 0; t < 1024; t++) {
    if (t > 0) {
      // 1) poll the 32 per-wave flags (one 128B coalesced line per iteration)
      const unsigned tgt = (unsigned)t;
      for (;;) {
        unsigned fv;
        asm volatile("global_load_dword %0, %1, off sc0 sc1\n\ts_waitcnt vmcnt(0)"
                     : "=v"(fv) : "v"(fp) : "memory");
        if (__all((int)(fv >= tgt))) break;
      }
      // 2) one bulk load of the 256-dword h state (this wave's ks-slice view)
      const unsigned* hs = hb + (((t - 1) & 1) << 8) + (ks << 5);
      asm volatile(
          "global_load_dwordx4 %0, %8, off sc0 sc1\n\t"
          "global_load_dwordx4 %1, %8, off offset:16 sc0 sc1\n\t"
          "global_load_dwordx4 %2, %8, off offset:32 sc0 sc1\n\t"
          "global_load_dwordx4 %3, %8, off offset:48 sc0 sc1\n\t"
          "global_load_dwordx4 %4, %8, off offset:64 sc0 sc1\n\t"
          "global_load_dwordx4 %5, %8, off offset:80 sc0 sc1\n\t"
          "global_load_dwordx4 %6, %8, off offset:96 sc0 sc1\n\t"
          "global_load_dwordx4 %7, %8, off offset:112 sc0 sc1\n\t"
          "s_waitcnt vmcnt(0)"
          : "=&v"(hr[0]), "=&v"(hr[1]), "=&v"(hr[2]), "=&v"(hr[3]),
            "=&v"(hr[4]), "=&v"(hr[5]), "=&v"(hr[6]), "=&v"(hr[7])
          : "v"(hs)
          : "memory");
    } else {
#pragma unroll
      for (int i = 0; i < 8; i++) hr[i] = (f32x4){0.f, 0.f, 0.f, 0.f};
    }

    float a0 = 0.f, a1 = 0.f, a2 = 0.f, a3 = 0.f;
#pragma unroll
    for (int i = 0; i < 8; i++)
#pragma unroll
      for (int m = 0; m < 4; m++) {
        // h dwords are bf16<<16: valid f32 bit patterns, used directly
        a0 = fmaf(w[0][i * 4 + m], hr[i][m], a0);
        a1 = fmaf(w[1][i * 4 + m], hr[i][m], a1);
        a2 = fmaf(w[2][i * 4 + m], hr[i][m], a2);
        a3 = fmaf(w[3][i * 4 + m], hr[i][m], a3);
      }
#pragma unroll
    for (int d = 1; d < 8; d <<= 1) {
      a0 += __shfl_xor(a0, d, 64);
      a1 += __shfl_xor(a1, d, 64);
      a2 += __shfl_xor(a2, d, 64);
      a3 += __shfl_xor(a3, d, 64);
    }

    float gf = a0 + xv0, gi = a1 + xv1, gg = a2 + xv2, go = a3 + xv3;
    float f = 1.f / (1.f + __expf(-gf));
    float ii = 1.f / (1.f + __expf(-gi));
    float eg = __expf(2.f * gg);
    float gt = (eg - 1.f) / (eg + 1.f);
    float o = 1.f / (1.f + __expf(-go));
    c = f * c + ii * gt;
    float ec = __expf(2.f * c);
    float tc = (ec - 1.f) / (ec + 1.f);
    float h = o * tc;

    // publish h (8 contiguous dwords per wave, merged store), drain, set flag
    if (ks == 0) {
      unsigned dw = (unsigned)f2bf(h) << 16;
      unsigned* hp = hb + ((t & 1) << 8) + gu;
      asm volatile("global_store_dword %0, %1, off sc0 sc1" ::"v"(hp), "v"(dw) : "memory");
    }
    asm volatile("s_waitcnt vmcnt(0)" ::: "memory");
    if (lane == 0) {
      unsigned fl = (unsigned)(t + 1);
      asm volatile("global_store_dword %0, %1, off sc0 sc1" ::"v"(fmine), "v"(fl) : "memory");
    }
    // off-critical-path output stores
    if (ks == 0) __builtin_nontemporal_store(h, &out[(xpb + t) * 256 + gu]);

    if (t < 1023) {
      const XPT* xr = &xp[(xpb + t + 1) * 1024 + gu];
      xv0 = xp_load(xr); xv1 = xp_load(xr + 256);
      xv2 = xp_load(xr + 512); xv3 = xp_load(xr + 768);
    } else if (ks == 0) {
      out[16777216 + b * 256 + gu] = h;           // h_fin
      out[16777216 + 16384 + b * 256 + gu] = c;   // c_fin
    }
  }
}

extern "C" void kernel_launch(void* const* d_in, const int* in_sizes, int n_in,
                              void* d_out, int out_size, void* d_ws, size_t ws_size,
                              hipStream_t stream) {
  (void)in_sizes; (void)n_in; (void)out_size;
  const float* x = (const float*)d_in[0];
  const float* W = (const float*)d_in[1];
  const float* bias = (const float*)d_in[2];
  float* out = (float*)d_out;
  char* ws = (char*)d_ws;

  unsigned int* Wx2 = (unsigned int*)ws;              // 524288 B
  unsigned int* hbuf = (unsigned int*)(ws + 524288);  // 131072 B (64 b x 2 x 256 dwords)
  unsigned int* flags = (unsigned int*)(ws + 655360); // 8192 B   (64 b x 32 waves)
  char* xpmem = ws + 1048576;

  const size_t need32 = 1048576 + (size_t)65536 * 1024 * 4;

  hipMemsetAsync(flags, 0, 8192, stream);  // stale flags must never validate (replay-safe)
  prep_wx<<<512, 256, 0, stream>>>(W, Wx2);

  if (ws_size >= need32) {
    gemm_xp<float><<<dim3(8, 512), 256, 0, stream>>>(x, Wx2, bias, (float*)xpmem);
    lstm_rec<float><<<256, 512, 0, stream>>>(W, (const float*)xpmem, out, hbuf, flags);
  } else {
    gemm_xp<unsigned short><<<dim3(8, 512), 256, 0, stream>>>(x, Wx2, bias,
                                                              (unsigned short*)xpmem);
    lstm_rec<unsigned short><<<256, 512, 0, stream>>>(W, (const unsigned short*)xpmem, out,
                                                      hbuf, flags);
  }
}

// Round 6
// 4706.475 us; speedup vs baseline: 1.9807x; 1.0441x over previous
//
#include <hip/hip_runtime.h>

typedef __attribute__((ext_vector_type(8))) short short8;
typedef __attribute__((ext_vector_type(4))) float f32x4;

__device__ __forceinline__ unsigned short f2bf(float f) {
  unsigned int u = __float_as_uint(f);
  u = (u + 0x7fffu + ((u >> 16) & 1u)) >> 16;
  return (unsigned short)u;
}

__device__ __forceinline__ void xp_store(float* p, float v) { *p = v; }
__device__ __forceinline__ void xp_store(unsigned short* p, float v) { *p = f2bf(v); }
__device__ __forceinline__ float xp_load(const float* p) { return *p; }
__device__ __forceinline__ float xp_load(const unsigned short* p) {
  return __uint_as_float(((unsigned int)*p) << 16);
}

// ---------------- prep: pack W_x (f32 -> bf16 pairs) ----------------
__global__ void prep_wx(const float* __restrict__ W, unsigned int* __restrict__ Wx2) {
  int i = blockIdx.x * 256 + threadIdx.x;  // 1024*128 dwords
  int g = i >> 7, kk = i & 127;
  float lo = W[(size_t)g * 512 + 256 + 2 * kk];
  float hi = W[(size_t)g * 512 + 256 + 2 * kk + 1];
  Wx2[i] = (unsigned int)f2bf(lo) | ((unsigned int)f2bf(hi) << 16);
}

// ---------------- GEMM: xp[m][g] = sum_k x[m][k] * Wx[g][k] + b[g] ----------------
template <typename XPT>
__global__ __launch_bounds__(256, 4) void gemm_xp(const float* __restrict__ x,
                                                  const unsigned int* __restrict__ Wx2,
                                                  const float* __restrict__ bias,
                                                  XPT* __restrict__ xp) {
  __shared__ unsigned short As[128][40];
  __shared__ unsigned short Bs[128][40];
  const int m0 = blockIdx.y * 128, n0 = blockIdx.x * 128;
  const int tid = threadIdx.x, lane = tid & 63, w = tid >> 6;
  const int wr = w >> 1, wc = w & 1;
  const int r16 = lane & 15, kq = lane >> 4;
  f32x4 acc[4][4];
#pragma unroll
  for (int m = 0; m < 4; m++)
#pragma unroll
    for (int n = 0; n < 4; n++)
#pragma unroll
      for (int j = 0; j < 4; j++) acc[m][n][j] = 0.f;

  for (int kb = 0; kb < 256; kb += 32) {
    __syncthreads();
#pragma unroll
    for (int i = 0; i < 4; i++) {
      int idx = tid + i * 256;
      int row = idx >> 3, c4 = idx & 7;
      float4 v = *(const float4*)(x + (size_t)(m0 + row) * 256 + kb + c4 * 4);
      ushort4 s;
      s.x = f2bf(v.x); s.y = f2bf(v.y); s.z = f2bf(v.z); s.w = f2bf(v.w);
      *(ushort4*)&As[row][c4 * 4] = s;
    }
#pragma unroll
    for (int i = 0; i < 2; i++) {
      int idx = tid + i * 256;
      int row = idx >> 2, c = idx & 3;
      uint4 v = *(const uint4*)(Wx2 + (size_t)(n0 + row) * 128 + (kb >> 1) + c * 4);
      *(uint4*)&Bs[row][c * 8] = v;
    }
    __syncthreads();
    short8 a[4], bb[4];
#pragma unroll
    for (int m = 0; m < 4; m++)
      a[m] = *(const short8*)&As[wr * 64 + m * 16 + r16][kq * 8];
#pragma unroll
    for (int n = 0; n < 4; n++)
      bb[n] = *(const short8*)&Bs[wc * 64 + n * 16 + r16][kq * 8];
#pragma unroll
    for (int m = 0; m < 4; m++)
#pragma unroll
      for (int n = 0; n < 4; n++)
        acc[m][n] = __builtin_amdgcn_mfma_f32_16x16x32_bf16(a[m], bb[n], acc[m][n], 0, 0, 0);
  }
#pragma unroll
  for (int n = 0; n < 4; n++) {
    int gn = n0 + wc * 64 + n * 16 + r16;
    float bi = bias[gn];
#pragma unroll
    for (int m = 0; m < 4; m++) {
      int gm = m0 + wr * 64 + m * 16 + kq * 4;
#pragma unroll
      for (int j = 0; j < 4; j++) {
        xp_store(&xp[(size_t)(gm + j) * 1024 + gn], acc[m][n][j] + bi);
      }
    }
  }
}

// ---------------- recurrence: flag + bulk-load exchange; NAMED-REGISTER weights ----
// 4 WGs per batch; WG q owns units [q*64, q*64+64). Thread (u=tid>>3, ks=tid&7) holds
// all four gate rows of unit u over K-slice [ks*32, ks*32+32) in THIRTY-TWO NAMED
// f32x4 SSA values (no private array -> cannot be demoted to scratch; verify
// VGPR_Count ~200). launch_bounds(512,2): 2 waves/EU -> 1 WG/CU, 256-VGPR budget.
// 3-round intra-8-lane butterfly -> every lane holds the unit's full f,i,g,o ->
// in-register c/h update (redundant x8, deterministic).
// Exchange per wave per step (device-scope sc0 sc1, placement-oblivious):
//   8 h dwords (bf16<<16) stored -> s_waitcnt vmcnt(0) -> per-wave flag := t+1.
// Consumers poll the 32 flags of their batch with ONE coalesced 128B load until all
// >= t, then ONE 8x dwordx4 bulk load. Skew <= 1 (flag=t+1 implies slot-(t-1) reads
// retired), so 2 slots suffice. Flags memset each launch (replay-safe).
template <typename XPT>
__global__ __launch_bounds__(512, 2) void lstm_rec(const float* __restrict__ W,
                                                   const XPT* __restrict__ xp,
                                                   float* __restrict__ out,
                                                   unsigned* __restrict__ hbuf,
                                                   unsigned* __restrict__ flags) {
  const int tid = threadIdx.x;
  const int b = blockIdx.x & 63, q = blockIdx.x >> 6;
  const int ks = tid & 7, u = tid >> 3;
  const int lane = tid & 63, wv = tid >> 6;
  const int gu = (q << 6) + u;

  // weights: 4 gate rows x 32-K-slice as 32 NAMED f32x4 values (128 VGPRs)
  const float* rp0 = W + (size_t)(0 * 256 + gu) * 512 + (ks << 5);
  const float* rp1 = W + (size_t)(1 * 256 + gu) * 512 + (ks << 5);
  const float* rp2 = W + (size_t)(2 * 256 + gu) * 512 + (ks << 5);
  const float* rp3 = W + (size_t)(3 * 256 + gu) * 512 + (ks << 5);
  f32x4 wA0 = *(const f32x4*)(rp0 + 0),  wA1 = *(const f32x4*)(rp0 + 4);
  f32x4 wA2 = *(const f32x4*)(rp0 + 8),  wA3 = *(const f32x4*)(rp0 + 12);
  f32x4 wA4 = *(const f32x4*)(rp0 + 16), wA5 = *(const f32x4*)(rp0 + 20);
  f32x4 wA6 = *(const f32x4*)(rp0 + 24), wA7 = *(const f32x4*)(rp0 + 28);
  f32x4 wB0 = *(const f32x4*)(rp1 + 0),  wB1 = *(const f32x4*)(rp1 + 4);
  f32x4 wB2 = *(const f32x4*)(rp1 + 8),  wB3 = *(const f32x4*)(rp1 + 12);
  f32x4 wB4 = *(const f32x4*)(rp1 + 16), wB5 = *(const f32x4*)(rp1 + 20);
  f32x4 wB6 = *(const f32x4*)(rp1 + 24), wB7 = *(const f32x4*)(rp1 + 28);
  f32x4 wC0 = *(const f32x4*)(rp2 + 0),  wC1 = *(const f32x4*)(rp2 + 4);
  f32x4 wC2 = *(const f32x4*)(rp2 + 8),  wC3 = *(const f32x4*)(rp2 + 12);
  f32x4 wC4 = *(const f32x4*)(rp2 + 16), wC5 = *(const f32x4*)(rp2 + 20);
  f32x4 wC6 = *(const f32x4*)(rp2 + 24), wC7 = *(const f32x4*)(rp2 + 28);
  f32x4 wD0 = *(const f32x4*)(rp3 + 0),  wD1 = *(const f32x4*)(rp3 + 4);
  f32x4 wD2 = *(const f32x4*)(rp3 + 8),  wD3 = *(const f32x4*)(rp3 + 12);
  f32x4 wD4 = *(const f32x4*)(rp3 + 16), wD5 = *(const f32x4*)(rp3 + 20);
  f32x4 wD6 = *(const f32x4*)(rp3 + 24), wD7 = *(const f32x4*)(rp3 + 28);

  unsigned* hb = hbuf + ((size_t)b << 9);          // 2 slots x 256 dwords
  const unsigned* fp = flags + b * 32 + (lane & 31);
  unsigned* fmine = flags + b * 32 + (q << 3) + wv;
  const size_t xpb = (size_t)b << 10;

  float xv0, xv1, xv2, xv3;
  {
    const XPT* xr = &xp[xpb * 1024 + gu];
    xv0 = xp_load(xr); xv1 = xp_load(xr + 256);
    xv2 = xp_load(xr + 512); xv3 = xp_load(xr + 768);
  }
  float c = 0.f;
  f32x4 h0, h1, h2, h3, h4, h5, h6, h7;

  for (int t = 0; t < 1024; t++) {
    if (t > 0) {
      // 1) poll the 32 per-wave flags (one 128B coalesced line per iteration)
      const unsigned tgt = (unsigned)t;
      for (;;) {
        unsigned fv;
        asm volatile("global_load_dword %0, %1, off sc0 sc1\n\ts_waitcnt vmcnt(0)"
                     : "=v"(fv) : "v"(fp) : "memory");
        if (__all((int)(fv >= tgt))) break;
      }
      // 2) one bulk load of this wave's 32-dword ks-slice of the 256-dword h state
      const unsigned* hs = hb + (((t - 1) & 1) << 8) + (ks << 5);
      asm volatile(
          "global_load_dwordx4 %0, %8, off sc0 sc1\n\t"
          "global_load_dwordx4 %1, %8, off offset:16 sc0 sc1\n\t"
          "global_load_dwordx4 %2, %8, off offset:32 sc0 sc1\n\t"
          "global_load_dwordx4 %3, %8, off offset:48 sc0 sc1\n\t"
          "global_load_dwordx4 %4, %8, off offset:64 sc0 sc1\n\t"
          "global_load_dwordx4 %5, %8, off offset:80 sc0 sc1\n\t"
          "global_load_dwordx4 %6, %8, off offset:96 sc0 sc1\n\t"
          "global_load_dwordx4 %7, %8, off offset:112 sc0 sc1\n\t"
          "s_waitcnt vmcnt(0)"
          : "=&v"(h0), "=&v"(h1), "=&v"(h2), "=&v"(h3),
            "=&v"(h4), "=&v"(h5), "=&v"(h6), "=&v"(h7)
          : "v"(hs)
          : "memory");
    } else {
      h0 = h1 = h2 = h3 = h4 = h5 = h6 = h7 = (f32x4){0.f, 0.f, 0.f, 0.f};
    }

    // dot: fully named, no arrays (h dwords are bf16<<16: valid f32 bit patterns)
    float a0 = 0.f, a1 = 0.f, a2 = 0.f, a3 = 0.f;
#define FMA4(ACC, WV, HV)                 \
  ACC = fmaf((WV)[0], (HV)[0], ACC);      \
  ACC = fmaf((WV)[1], (HV)[1], ACC);      \
  ACC = fmaf((WV)[2], (HV)[2], ACC);      \
  ACC = fmaf((WV)[3], (HV)[3], ACC);
    FMA4(a0, wA0, h0) FMA4(a0, wA1, h1) FMA4(a0, wA2, h2) FMA4(a0, wA3, h3)
    FMA4(a0, wA4, h4) FMA4(a0, wA5, h5) FMA4(a0, wA6, h6) FMA4(a0, wA7, h7)
    FMA4(a1, wB0, h0) FMA4(a1, wB1, h1) FMA4(a1, wB2, h2) FMA4(a1, wB3, h3)
    FMA4(a1, wB4, h4) FMA4(a1, wB5, h5) FMA4(a1, wB6, h6) FMA4(a1, wB7, h7)
    FMA4(a2, wC0, h0) FMA4(a2, wC1, h1) FMA4(a2, wC2, h2) FMA4(a2, wC3, h3)
    FMA4(a2, wC4, h4) FMA4(a2, wC5, h5) FMA4(a2, wC6, h6) FMA4(a2, wC7, h7)
    FMA4(a3, wD0, h0) FMA4(a3, wD1, h1) FMA4(a3, wD2, h2) FMA4(a3, wD3, h3)
    FMA4(a3, wD4, h4) FMA4(a3, wD5, h5) FMA4(a3, wD6, h6) FMA4(a3, wD7, h7)
#undef FMA4
#pragma unroll
    for (int d = 1; d < 8; d <<= 1) {
      a0 += __shfl_xor(a0, d, 64);
      a1 += __shfl_xor(a1, d, 64);
      a2 += __shfl_xor(a2, d, 64);
      a3 += __shfl_xor(a3, d, 64);
    }

    float gf = a0 + xv0, gi = a1 + xv1, gg = a2 + xv2, go = a3 + xv3;
    float f = 1.f / (1.f + __expf(-gf));
    float ii = 1.f / (1.f + __expf(-gi));
    float eg = __expf(2.f * gg);
    float gt = (eg - 1.f) / (eg + 1.f);
    float o = 1.f / (1.f + __expf(-go));
    c = f * c + ii * gt;
    float ec = __expf(2.f * c);
    float tc = (ec - 1.f) / (ec + 1.f);
    float h = o * tc;

    // publish h (8 contiguous dwords per wave), drain, set flag
    if (ks == 0) {
      unsigned dw = (unsigned)f2bf(h) << 16;
      unsigned* hp = hb + ((t & 1) << 8) + gu;
      asm volatile("global_store_dword %0, %1, off sc0 sc1" ::"v"(hp), "v"(dw) : "memory");
    }
    asm volatile("s_waitcnt vmcnt(0)" ::: "memory");
    if (lane == 0) {
      unsigned fl = (unsigned)(t + 1);
      asm volatile("global_store_dword %0, %1, off sc0 sc1" ::"v"(fmine), "v"(fl) : "memory");
    }
    // off-critical-path output stores
    if (ks == 0) __builtin_nontemporal_store(h, &out[(xpb + t) * 256 + gu]);

    if (t < 1023) {
      const XPT* xr = &xp[(xpb + t + 1) * 1024 + gu];
      xv0 = xp_load(xr); xv1 = xp_load(xr + 256);
      xv2 = xp_load(xr + 512); xv3 = xp_load(xr + 768);
    } else if (ks == 0) {
      out[16777216 + b * 256 + gu] = h;           // h_fin
      out[16777216 + 16384 + b * 256 + gu] = c;   // c_fin
    }
  }
}

extern "C" void kernel_launch(void* const* d_in, const int* in_sizes, int n_in,
                              void* d_out, int out_size, void* d_ws, size_t ws_size,
                              hipStream_t stream) {
  (void)in_sizes; (void)n_in; (void)out_size;
  const float* x = (const float*)d_in[0];
  const float* W = (const float*)d_in[1];
  const float* bias = (const float*)d_in[2];
  float* out = (float*)d_out;
  char* ws = (char*)d_ws;

  unsigned int* Wx2 = (unsigned int*)ws;              // 524288 B
  unsigned int* hbuf = (unsigned int*)(ws + 524288);  // 131072 B (64 b x 2 x 256 dwords)
  unsigned int* flags = (unsigned int*)(ws + 655360); // 8192 B   (64 b x 32 waves)
  char* xpmem = ws + 1048576;

  const size_t need32 = 1048576 + (size_t)65536 * 1024 * 4;

  hipMemsetAsync(flags, 0, 8192, stream);  // stale flags must never validate (replay-safe)
  prep_wx<<<512, 256, 0, stream>>>(W, Wx2);

  if (ws_size >= need32) {
    gemm_xp<float><<<dim3(8, 512), 256, 0, stream>>>(x, Wx2, bias, (float*)xpmem);
    lstm_rec<float><<<256, 512, 0, stream>>>(W, (const float*)xpmem, out, hbuf, flags);
  } else {
    gemm_xp<unsigned short><<<dim3(8, 512), 256, 0, stream>>>(x, Wx2, bias,
                                                              (unsigned short*)xpmem);
    lstm_rec<unsigned short><<<256, 512, 0, stream>>>(W, (const unsigned short*)xpmem, out,
                                                      hbuf, flags);
  }
}